// Round 3
// baseline (602.262 us; speedup 1.0000x reference)
//
#include <hip/hip_runtime.h>
#include <math.h>

#define NCLU 10
#define D    64
#define NSLOT 4096

// dot of a 64-float LDS row (wave-uniform -> broadcast) with a 64-float global row
__device__ __forceinline__ float dot64f(const float* __restrict__ x, const float* __restrict__ w) {
    const float4* w4 = (const float4*)w;
    const float4* x4 = (const float4*)x;
    float a0 = 0.f, a1 = 0.f, a2 = 0.f, a3 = 0.f;
#pragma unroll
    for (int jj = 0; jj < 16; ++jj) {
        float4 wv = w4[jj], xv = x4[jj];
        a0 += wv.x * xv.x; a1 += wv.y * xv.y; a2 += wv.z * xv.z; a3 += wv.w * xv.w;
    }
    return (a0 + a1) + (a2 + a3);
}

__device__ __forceinline__ float dot128f(const float* __restrict__ x, const float* __restrict__ w) {
    const float4* w4 = (const float4*)w;
    const float4* x4 = (const float4*)x;
    float a0 = 0.f, a1 = 0.f, a2 = 0.f, a3 = 0.f;
#pragma unroll
    for (int jj = 0; jj < 32; ++jj) {
        float4 wv = w4[jj], xv = x4[jj];
        a0 += wv.x * xv.x; a1 += wv.y * xv.y; a2 += wv.z * xv.z; a3 += wv.w * xv.w;
    }
    return (a0 + a1) + (a2 + a3);
}

// 64-lane wave reduction (wavefront = 64 on CDNA)
__device__ __forceinline__ float wred(float v) {
#pragma unroll
    for (int off = 32; off > 0; off >>= 1) v += __shfl_xor(v, off);
    return v;
}

// ---------------- Phase 1: 3-iteration slot-attention refinement ----------------
// 1 block x 640 threads; thread t -> (cluster n = t>>6, dim i = t&63); one wave per row.
__global__ __launch_bounds__(640) void phase1_kernel(
    const float* __restrict__ cc0,
    const float* __restrict__ Wk, const float* __restrict__ bk,
    const float* __restrict__ Wq, const float* __restrict__ bq,
    const float* __restrict__ Wv, const float* __restrict__ bv,
    const float* __restrict__ cc_g, const float* __restrict__ cc_b,
    const float* __restrict__ W_ih, const float* __restrict__ W_hh,
    const float* __restrict__ b_ih, const float* __restrict__ b_hh,
    const float* __restrict__ ln_g, const float* __restrict__ ln_b,
    const float* __restrict__ W1, const float* __restrict__ b1,
    const float* __restrict__ W2, const float* __restrict__ b2,
    float* __restrict__ cc_out)
{
    const int t = threadIdx.x;
    const int n = t >> 6;
    const int i = t & 63;

    __shared__ float ccl[NCLU][64];   // current cc (prev at GRU time)
    __shared__ float xl[NCLU][64];    // LN(cc) for q
    __shared__ float kl[NCLU][64];
    __shared__ float vl[NCLU][64];
    __shared__ float ql[NCLU][68];    // padded; 68*4B rows stay 16B-aligned
    __shared__ float al[NCLU][12];    // attn matrix
    __shared__ float ul[NCLU][64];    // updates
    __shared__ float hl[NCLU][64];    // MLP LN out
    __shared__ float tl[NCLU][128];   // MLP hidden

    // per-thread persistent bias/gain loads
    const float g_cc = cc_g[i], b_cc = cc_b[i];
    const float g_ln = ln_g[i], b_ln = ln_b[i];
    const float bq_i = bq[i];
    const float bih0 = b_ih[i], bih1 = b_ih[64 + i], bih2 = b_ih[128 + i];
    const float bhh0 = b_hh[i], bhh1 = b_hh[64 + i], bhh2 = b_hh[128 + i];
    const float b1a = b1[i], b1b = b1[64 + i];
    const float b2_i = b2[i];

    float c = cc0[n * 64 + i];
    ccl[n][i] = c;
    __syncthreads();

    // k, v from ORIGINAL cluster_centers
    {
        float kk = dot64f(&ccl[n][0], Wk + i * 64) + bk[i];
        float vv = dot64f(&ccl[n][0], Wv + i * 64) + bv[i];
        kl[n][i] = kk;
        vl[n][i] = vv;
    }
    __syncthreads();

    for (int it = 0; it < 3; ++it) {
        // ---- LN(cc) with cc_g/cc_b (one wave == one row; shuffle reduce) ----
        {
            float s1 = wred(c), s2 = wred(c * c);
            float mu = s1 * (1.f / 64.f);
            float va = s2 * (1.f / 64.f) - mu * mu;
            float x = (c - mu) * rsqrtf(va + 1e-5f) * g_cc + b_cc;
            xl[n][i] = x;
        }
        __syncthreads();

        // ---- q = LN(cc) @ Wq^T + bq ----
        ql[n][i] = dot64f(&xl[n][0], Wq + i * 64) + bq_i;
        __syncthreads();

        // ---- attn[n][m] = temp * <k[n], q[m]> (lanes m<10 active) ----
        if (i < NCLU) {
            const float4* kf = (const float4*)&kl[n][0];
            const float4* qf = (const float4*)&ql[i][0];
            float a0 = 0.f, a1 = 0.f, a2 = 0.f, a3 = 0.f;
#pragma unroll
            for (int jj = 0; jj < 16; ++jj) {
                float4 kv = kf[jj], qv = qf[jj];
                a0 += kv.x * qv.x; a1 += kv.y * qv.y; a2 += kv.z * qv.z; a3 += kv.w * qv.w;
            }
            al[n][i] = ((a0 + a1) + (a2 + a3)) * 0.125f;   // temp = 64^-0.5
        }
        __syncthreads();

        // ---- softmax over axis 0 (columns), + EPS ----
        if (t < NCLU) {  // column m = t
            float mx = -1e30f;
#pragma unroll
            for (int nn = 0; nn < NCLU; ++nn) mx = fmaxf(mx, al[nn][t]);
            float e[NCLU]; float s = 0.f;
#pragma unroll
            for (int nn = 0; nn < NCLU; ++nn) { e[nn] = __expf(al[nn][t] - mx); s += e[nn]; }
            float inv = 1.f / s;
#pragma unroll
            for (int nn = 0; nn < NCLU; ++nn) al[nn][t] = e[nn] * inv + 1e-8f;
        }
        __syncthreads();
        // ---- row renormalize (axis -1) ----
        if (t < NCLU) {  // row n = t
            float s = 0.f;
#pragma unroll
            for (int m = 0; m < NCLU; ++m) s += al[t][m];
            float inv = 1.f / s;
#pragma unroll
            for (int m = 0; m < NCLU; ++m) al[t][m] *= inv;
        }
        __syncthreads();

        // ---- updates = attn @ v ----
        {
            float u = 0.f;
#pragma unroll
            for (int m = 0; m < NCLU; ++m) u += al[n][m] * vl[m][i];
            ul[n][i] = u;
        }
        __syncthreads();

        // ---- GRU cell ----
        {
            float ir  = dot64f(&ul[n][0],  W_ih + i * 64)          + bih0;
            float iz  = dot64f(&ul[n][0],  W_ih + (64 + i) * 64)   + bih1;
            float inn = dot64f(&ul[n][0],  W_ih + (128 + i) * 64)  + bih2;
            float hr  = dot64f(&ccl[n][0], W_hh + i * 64)          + bhh0;
            float hz  = dot64f(&ccl[n][0], W_hh + (64 + i) * 64)   + bhh1;
            float hn  = dot64f(&ccl[n][0], W_hh + (128 + i) * 64)  + bhh2;
            float r = 1.f / (1.f + __expf(-(ir + hr)));
            float z = 1.f / (1.f + __expf(-(iz + hz)));
            float nn2 = tanhf(inn + r * hn);
            c = (1.f - z) * nn2 + z * c;
        }

        // ---- residual MLP: LN ----
        {
            float s1 = wred(c), s2 = wred(c * c);
            float mu = s1 * (1.f / 64.f);
            float va = s2 * (1.f / 64.f) - mu * mu;
            float h = (c - mu) * rsqrtf(va + 1e-5f) * g_ln + b_ln;
            hl[n][i] = h;
        }
        __syncthreads();
        // ---- hidden = relu(h @ W1^T + b1) ----
        {
            float t1a = fmaxf(dot64f(&hl[n][0], W1 + i * 64)        + b1a, 0.f);
            float t1b = fmaxf(dot64f(&hl[n][0], W1 + (64 + i) * 64) + b1b, 0.f);
            tl[n][i]      = t1a;
            tl[n][64 + i] = t1b;
        }
        __syncthreads();
        // ---- cc = cc + hidden @ W2^T + b2 ----
        c = c + dot128f(&tl[n][0], W2 + i * 128) + b2_i;
        ccl[n][i] = c;
        __syncthreads();
    }

    cc_out[n * 64 + i] = c;
}

// ---------------- Phase 2: per-slot MLP + max over clusters ----------------
// 4096 blocks x 64 threads (one wave per slot). Thread i owns row i of Wa[s], Wb[s].
// HBM-bound: streams 134 MB of f32 weights with fully-coalesced float4 row loads.
// Streaming-accumulator form: each loaded float4 of the weight row feeds all 10
// cluster dots immediately -> peak live VGPRs ~50, no spills at 16 waves/CU.
__global__ __launch_bounds__(64, 4) void phase2_kernel(
    const float* __restrict__ Wa, const float* __restrict__ ba,
    const float* __restrict__ Wb, const float* __restrict__ bb,
    const float* __restrict__ cc, float* __restrict__ out)
{
    const int s = blockIdx.x;
    const int i = threadIdx.x;

    __shared__ float ccl[NCLU * 64];
    __shared__ float hlds[NCLU * 64];

    // stage cc once (f32 from phase 1)
#pragma unroll
    for (int nn = 0; nn < NCLU; ++nn) ccl[nn * 64 + i] = cc[nn * 64 + i];
    __syncthreads();

    const float4* wa4 = (const float4*)(Wa + (size_t)s * 4096 + (size_t)i * 64);
    const float4* wb4 = (const float4*)(Wb + (size_t)s * 4096 + (size_t)i * 64);
    const float4* cc4 = (const float4*)ccl;
    const float4* hh4 = (const float4*)hlds;

    const float ba_i = ba[s * 64 + i];

    // layer 1: h[n] = relu(<Wa[s] row i, cc[n,:]> + ba[s,i])
    float acc[NCLU];
#pragma unroll
    for (int nn = 0; nn < NCLU; ++nn) acc[nn] = 0.f;
#pragma unroll
    for (int jj = 0; jj < 16; ++jj) {
        float4 wv = wa4[jj];
#pragma unroll
        for (int nn = 0; nn < NCLU; ++nn) {
            float4 xv = cc4[nn * 16 + jj];   // wave-uniform address -> LDS broadcast
            acc[nn] += wv.x * xv.x + wv.y * xv.y + wv.z * xv.z + wv.w * xv.w;
        }
    }
#pragma unroll
    for (int nn = 0; nn < NCLU; ++nn)
        hlds[nn * 64 + i] = fmaxf(acc[nn] + ba_i, 0.f);
    __syncthreads();

    // layer 2 + max over clusters
#pragma unroll
    for (int nn = 0; nn < NCLU; ++nn) acc[nn] = 0.f;
#pragma unroll
    for (int jj = 0; jj < 16; ++jj) {
        float4 wv = wb4[jj];
#pragma unroll
        for (int nn = 0; nn < NCLU; ++nn) {
            float4 xv = hh4[nn * 16 + jj];
            acc[nn] += wv.x * xv.x + wv.y * xv.y + wv.z * xv.z + wv.w * xv.w;
        }
    }
    float mx = acc[0];
#pragma unroll
    for (int nn = 1; nn < NCLU; ++nn) mx = fmaxf(mx, acc[nn]);

    out[s * 64 + i] = mx + bb[s * 64 + i];
}

extern "C" void kernel_launch(void* const* d_in, const int* in_sizes, int n_in,
                              void* d_out, int out_size, void* d_ws, size_t ws_size,
                              hipStream_t stream) {
    const float* cc0  = (const float*)d_in[0];
    const float* Wk   = (const float*)d_in[1];
    const float* bk   = (const float*)d_in[2];
    const float* Wq   = (const float*)d_in[3];
    const float* bq   = (const float*)d_in[4];
    const float* Wv   = (const float*)d_in[5];
    const float* bv   = (const float*)d_in[6];
    const float* ccg  = (const float*)d_in[7];
    const float* ccb  = (const float*)d_in[8];
    const float* Wih  = (const float*)d_in[9];
    const float* Whh  = (const float*)d_in[10];
    const float* bih  = (const float*)d_in[11];
    const float* bhh  = (const float*)d_in[12];
    const float* lng  = (const float*)d_in[13];
    const float* lnb  = (const float*)d_in[14];
    const float* W1   = (const float*)d_in[15];
    const float* b1   = (const float*)d_in[16];
    const float* W2   = (const float*)d_in[17];
    const float* b2   = (const float*)d_in[18];
    const float* Wa   = (const float*)d_in[19];
    const float* ba   = (const float*)d_in[20];
    const float* Wb   = (const float*)d_in[21];
    const float* bb   = (const float*)d_in[22];

    float* cc_ws = (float*)d_ws;     // 640 floats
    float* out   = (float*)d_out;

    hipLaunchKernelGGL(phase1_kernel, dim3(1), dim3(640), 0, stream,
                       cc0, Wk, bk, Wq, bq, Wv, bv, ccg, ccb,
                       Wih, Whh, bih, bhh, lng, lnb, W1, b1, W2, b2, cc_ws);

    hipLaunchKernelGGL(phase2_kernel, dim3(NSLOT), dim3(64), 0, stream,
                       Wa, ba, Wb, bb, cc_ws, out);
}

// Round 4
// 289.376 us; speedup vs baseline: 2.0812x; 2.0812x over previous
//
#include <hip/hip_runtime.h>
#include <math.h>

#define NCLU 10
#define D    64
#define NSLOT 4096

// broadcast-x dot: xrow is a wave-uniform 16B-aligned LDS row (64 floats),
// wr is 64 per-lane registers (this lane's weight row). 4 accumulators for ILP.
__device__ __forceinline__ float dot_bcast64(const float* __restrict__ xrow, const float* wr) {
    const float4* x4 = (const float4*)xrow;
    float a0 = 0.f, a1 = 0.f, a2 = 0.f, a3 = 0.f;
#pragma unroll
    for (int jj = 0; jj < 16; ++jj) {
        float4 xv = x4[jj];
        a0 += wr[jj * 4 + 0] * xv.x;
        a1 += wr[jj * 4 + 1] * xv.y;
        a2 += wr[jj * 4 + 2] * xv.z;
        a3 += wr[jj * 4 + 3] * xv.w;
    }
    return (a0 + a1) + (a2 + a3);
}

__device__ __forceinline__ float dot_bcast128(const float* __restrict__ xrow, const float* wr) {
    const float4* x4 = (const float4*)xrow;
    float a0 = 0.f, a1 = 0.f, a2 = 0.f, a3 = 0.f;
#pragma unroll
    for (int jj = 0; jj < 32; ++jj) {
        float4 xv = x4[jj];
        a0 += wr[jj * 4 + 0] * xv.x;
        a1 += wr[jj * 4 + 1] * xv.y;
        a2 += wr[jj * 4 + 2] * xv.z;
        a3 += wr[jj * 4 + 3] * xv.w;
    }
    return (a0 + a1) + (a2 + a3);
}

// one-time scattered row load (lane i's row -> 64 regs)
__device__ __forceinline__ void load_row64(float* r, const float* __restrict__ Wrow) {
    const float4* p = (const float4*)Wrow;
#pragma unroll
    for (int jj = 0; jj < 16; ++jj) {
        float4 v = p[jj];
        r[jj * 4 + 0] = v.x; r[jj * 4 + 1] = v.y; r[jj * 4 + 2] = v.z; r[jj * 4 + 3] = v.w;
    }
}

// 64-lane wave reduction
__device__ __forceinline__ float wred(float v) {
#pragma unroll
    for (int off = 32; off > 0; off >>= 1) v += __shfl_xor(v, off);
    return v;
}

// ---------------- Phase 1: weight-stationary slot-attention refinement ----------------
// 1 block x 640 threads = 10 waves. Wave w (= cluster n for elementwise work) also owns
// one weight block in registers:
//   w0: Wq | w1-3: W_ih blocks (ir,iz,in) | w4-6: W_hh blocks (hr,hz,hn)
//   w7: Wk then W1[0:64] | w8: Wv then W1[64:128] | w9: W2 (64x128, 128 regs)
__global__ __launch_bounds__(640) void phase1_kernel(
    const float* __restrict__ cc0,
    const float* __restrict__ Wk, const float* __restrict__ bk,
    const float* __restrict__ Wq, const float* __restrict__ bq,
    const float* __restrict__ Wv, const float* __restrict__ bv,
    const float* __restrict__ cc_g, const float* __restrict__ cc_b,
    const float* __restrict__ W_ih, const float* __restrict__ W_hh,
    const float* __restrict__ b_ih, const float* __restrict__ b_hh,
    const float* __restrict__ ln_g, const float* __restrict__ ln_b,
    const float* __restrict__ W1, const float* __restrict__ b1,
    const float* __restrict__ W2, const float* __restrict__ b2,
    float* __restrict__ cc_out)
{
    const int t = threadIdx.x;
    const int w = t >> 6;    // wave id == cluster n for elementwise phases
    const int i = t & 63;    // lane

    __shared__ float ccl[NCLU][64];
    __shared__ float xl[NCLU][64];
    __shared__ float kl[NCLU][64];
    __shared__ float vl[NCLU][64];
    __shared__ float ql[NCLU][68];      // padded rows for per-lane reads in attn
    __shared__ float al[NCLU][12];
    __shared__ float ul[NCLU][64];
    __shared__ float hl[NCLU][64];
    __shared__ float tl[NCLU][128];
    __shared__ float gl[6][NCLU][64];   // ir,iz,in,hr,hz,hn
    __shared__ float dl[NCLU][64];      // W2 output (incl b2)

    // elementwise constants (all threads)
    const float g_cc = cc_g[i], b_cc = cc_b[i];
    const float g_ln = ln_g[i], b_ln = ln_b[i];

    // role-specific bias + weight block
    float wreg[128];
    float bias0 = 0.f, biask = 0.f;
    if (w == 0)      { load_row64(wreg, Wq + i * 64);                 bias0 = bq[i]; }
    else if (w <= 3) { load_row64(wreg, W_ih + ((w - 1) * 64 + i) * 64); bias0 = b_ih[(w - 1) * 64 + i]; }
    else if (w <= 6) { load_row64(wreg, W_hh + ((w - 4) * 64 + i) * 64); bias0 = b_hh[(w - 4) * 64 + i]; }
    else if (w == 7) { load_row64(wreg, Wk + i * 64);                 biask = bk[i]; }
    else if (w == 8) { load_row64(wreg, Wv + i * 64);                 biask = bv[i]; }
    else {  // w == 9: W2 row i (128 wide)
        const float4* p = (const float4*)(W2 + i * 128);
#pragma unroll
        for (int jj = 0; jj < 32; ++jj) {
            float4 v = p[jj];
            wreg[jj * 4 + 0] = v.x; wreg[jj * 4 + 1] = v.y;
            wreg[jj * 4 + 2] = v.z; wreg[jj * 4 + 3] = v.w;
        }
        bias0 = b2[i];
    }

    float c = cc0[w * 64 + i];
    ccl[w][i] = c;
    __syncthreads();

    // k, v from original cluster_centers (w7/w8 own Wk/Wv)
    if (w == 7) {
#pragma unroll
        for (int n = 0; n < NCLU; ++n) kl[n][i] = dot_bcast64(&ccl[n][0], wreg) + biask;
    } else if (w == 8) {
#pragma unroll
        for (int n = 0; n < NCLU; ++n) vl[n][i] = dot_bcast64(&ccl[n][0], wreg) + biask;
    }
    __syncthreads();

    // w7/w8 now swap their blocks for W1 halves (loads overlap with iter-1 attention)
    if (w == 7)      { load_row64(wreg, W1 + i * 64);        bias0 = b1[i]; }
    else if (w == 8) { load_row64(wreg, W1 + (64 + i) * 64); bias0 = b1[64 + i]; }

    for (int it = 0; it < 3; ++it) {
        // ---- LN(cc) with cc_g/cc_b (wave == row; shuffle reduce) ----
        {
            float s1 = wred(c), s2 = wred(c * c);
            float mu = s1 * (1.f / 64.f);
            float va = s2 * (1.f / 64.f) - mu * mu;
            xl[w][i] = (c - mu) * rsqrtf(va + 1e-5f) * g_cc + b_cc;
        }
        __syncthreads();

        // ---- q (w0, from xl)  CONCURRENT WITH  gh gates (w4-6, from prev ccl) ----
        if (w == 0) {
#pragma unroll
            for (int n = 0; n < NCLU; ++n) ql[n][i] = dot_bcast64(&xl[n][0], wreg) + bias0;
        } else if (w >= 4 && w <= 6) {
#pragma unroll
            for (int n = 0; n < NCLU; ++n) gl[w - 1][n][i] = dot_bcast64(&ccl[n][0], wreg) + bias0;
        }
        __syncthreads();

        // ---- attn[n][m] = temp * <k[n], q[m]>, lane m<10, wave n ----
        if (i < NCLU) {
            const float4* kf = (const float4*)&kl[w][0];   // wave-uniform -> broadcast
            const float4* qf = (const float4*)&ql[i][0];   // per-lane row, 68-stride
            float a0 = 0.f, a1 = 0.f, a2 = 0.f, a3 = 0.f;
#pragma unroll
            for (int jj = 0; jj < 16; ++jj) {
                float4 kv = kf[jj], qv = qf[jj];
                a0 += kv.x * qv.x; a1 += kv.y * qv.y; a2 += kv.z * qv.z; a3 += kv.w * qv.w;
            }
            al[w][i] = ((a0 + a1) + (a2 + a3)) * 0.125f;   // temp = 64^-0.5
        }
        __syncthreads();

        // ---- softmax over axis 0 (columns) + EPS ----
        if (t < NCLU) {
            float mx = -1e30f;
#pragma unroll
            for (int nn = 0; nn < NCLU; ++nn) mx = fmaxf(mx, al[nn][t]);
            float e[NCLU]; float s = 0.f;
#pragma unroll
            for (int nn = 0; nn < NCLU; ++nn) { e[nn] = __expf(al[nn][t] - mx); s += e[nn]; }
            float inv = 1.f / s;
#pragma unroll
            for (int nn = 0; nn < NCLU; ++nn) al[nn][t] = e[nn] * inv + 1e-8f;
        }
        __syncthreads();
        // ---- row renormalize (axis -1) ----
        if (t < NCLU) {
            float s = 0.f;
#pragma unroll
            for (int m = 0; m < NCLU; ++m) s += al[t][m];
            float inv = 1.f / s;
#pragma unroll
            for (int m = 0; m < NCLU; ++m) al[t][m] *= inv;
        }
        __syncthreads();

        // ---- updates = attn @ v ----
        {
            float u = 0.f;
#pragma unroll
            for (int m = 0; m < NCLU; ++m) u += al[w][m] * vl[m][i];
            ul[w][i] = u;
        }
        __syncthreads();

        // ---- gi gates (w1-3, from ul) ----
        if (w >= 1 && w <= 3) {
#pragma unroll
            for (int n = 0; n < NCLU; ++n) gl[w - 1][n][i] = dot_bcast64(&ul[n][0], wreg) + bias0;
        }
        __syncthreads();

        // ---- GRU combine (wave == row) ----
        {
            float ir = gl[0][w][i], iz = gl[1][w][i], inn = gl[2][w][i];
            float hr = gl[3][w][i], hz = gl[4][w][i], hn = gl[5][w][i];
            float r = 1.f / (1.f + __expf(-(ir + hr)));
            float z = 1.f / (1.f + __expf(-(iz + hz)));
            float nn2 = tanhf(inn + r * hn);
            c = (1.f - z) * nn2 + z * c;
        }

        // ---- residual MLP: LN ----
        {
            float s1 = wred(c), s2 = wred(c * c);
            float mu = s1 * (1.f / 64.f);
            float va = s2 * (1.f / 64.f) - mu * mu;
            hl[w][i] = (c - mu) * rsqrtf(va + 1e-5f) * g_ln + b_ln;
        }
        __syncthreads();

        // ---- hidden = relu(h @ W1^T + b1): w7 -> tl[:, 0:64], w8 -> tl[:, 64:128] ----
        if (w == 7) {
#pragma unroll
            for (int n = 0; n < NCLU; ++n) tl[n][i] = fmaxf(dot_bcast64(&hl[n][0], wreg) + bias0, 0.f);
        } else if (w == 8) {
#pragma unroll
            for (int n = 0; n < NCLU; ++n) tl[n][64 + i] = fmaxf(dot_bcast64(&hl[n][0], wreg) + bias0, 0.f);
        }
        __syncthreads();

        // ---- delta = hidden @ W2^T + b2 (w9) ----
        if (w == 9) {
#pragma unroll
            for (int n = 0; n < NCLU; ++n) dl[n][i] = dot_bcast128(&tl[n][0], wreg) + bias0;
        }
        __syncthreads();

        // ---- residual add, commit cc ----
        c += dl[w][i];
        ccl[w][i] = c;
        __syncthreads();
    }

    cc_out[w * 64 + i] = c;
}

// ---------------- Phase 2: per-slot MLP + max over clusters ----------------
// 4096 blocks x 64 threads (1 wave per slot). Weights loaded COALESCED
// (lane l reads float4 at flat offset c*1024B + l*16B), transposed to per-lane
// rows via a padded (stride-68) LDS buffer, then broadcast-dot vs cc / h.
// HBM-bound: 134 MB of f32 weights streamed once, ~21 us floor.
__global__ __launch_bounds__(64) void phase2_kernel(
    const float* __restrict__ Wa, const float* __restrict__ ba,
    const float* __restrict__ Wb, const float* __restrict__ bb,
    const float* __restrict__ cc, float* __restrict__ out)
{
    const int s = blockIdx.x;
    const int l = threadIdx.x;

    __shared__ float ccl[NCLU * 64];
    __shared__ float hlds[NCLU * 64];
    __shared__ float stg[64 * 68];      // padded rows: stride 68 floats (272 B, 16B-aligned)

    const float* wa = Wa + (size_t)s * 4096;
    const float* wb = Wb + (size_t)s * 4096;

    // issue BOTH weight streams up-front (32 independent coalesced 1KB loads/wave)
    float4 rga[16], rgb[16];
#pragma unroll
    for (int cchunk = 0; cchunk < 16; ++cchunk)
        rga[cchunk] = *(const float4*)(wa + cchunk * 256 + l * 4);
#pragma unroll
    for (int cchunk = 0; cchunk < 16; ++cchunk)
        rgb[cchunk] = *(const float4*)(wb + cchunk * 256 + l * 4);

    // stage cc (tiny, L2-resident)
#pragma unroll
    for (int nn = 0; nn < NCLU; ++nn) ccl[nn * 64 + l] = cc[nn * 64 + l];

    const float ba_i = ba[s * 64 + l];
    const float bb_i = bb[s * 64 + l];

    // flat element f = cchunk*256 + l*4  ->  row r = cchunk*4 + (l>>4), col = (l&15)*4
    const int r0  = l >> 4;
    const int col = (l & 15) * 4;

    // ---- transpose Wa into padded LDS, read back row l ----
#pragma unroll
    for (int cchunk = 0; cchunk < 16; ++cchunk)
        *(float4*)(&stg[(cchunk * 4 + r0) * 68 + col]) = rga[cchunk];
    __syncthreads();

    float wr[64];
    {
        const float4* rp = (const float4*)(&stg[l * 68]);
#pragma unroll
        for (int jj = 0; jj < 16; ++jj) {
            float4 v = rp[jj];
            wr[jj * 4 + 0] = v.x; wr[jj * 4 + 1] = v.y; wr[jj * 4 + 2] = v.z; wr[jj * 4 + 3] = v.w;
        }
    }

    // ---- layer 1: h[n] = relu(<Wa row l, cc[n,:]> + ba) ----
    float acc[NCLU];
#pragma unroll
    for (int nn = 0; nn < NCLU; ++nn) acc[nn] = dot_bcast64(&ccl[nn * 64], wr);
#pragma unroll
    for (int nn = 0; nn < NCLU; ++nn) hlds[nn * 64 + l] = fmaxf(acc[nn] + ba_i, 0.f);
    __syncthreads();

    // ---- transpose Wb into (reused) LDS, read back row l ----
#pragma unroll
    for (int cchunk = 0; cchunk < 16; ++cchunk)
        *(float4*)(&stg[(cchunk * 4 + r0) * 68 + col]) = rgb[cchunk];
    __syncthreads();
    {
        const float4* rp = (const float4*)(&stg[l * 68]);
#pragma unroll
        for (int jj = 0; jj < 16; ++jj) {
            float4 v = rp[jj];
            wr[jj * 4 + 0] = v.x; wr[jj * 4 + 1] = v.y; wr[jj * 4 + 2] = v.z; wr[jj * 4 + 3] = v.w;
        }
    }

    // ---- layer 2 + max over clusters ----
    float mx = -1e30f;
#pragma unroll
    for (int nn = 0; nn < NCLU; ++nn)
        mx = fmaxf(mx, dot_bcast64(&hlds[nn * 64], wr));

    out[s * 64 + l] = mx + bb_i;
}

extern "C" void kernel_launch(void* const* d_in, const int* in_sizes, int n_in,
                              void* d_out, int out_size, void* d_ws, size_t ws_size,
                              hipStream_t stream) {
    const float* cc0  = (const float*)d_in[0];
    const float* Wk   = (const float*)d_in[1];
    const float* bk   = (const float*)d_in[2];
    const float* Wq   = (const float*)d_in[3];
    const float* bq   = (const float*)d_in[4];
    const float* Wv   = (const float*)d_in[5];
    const float* bv   = (const float*)d_in[6];
    const float* ccg  = (const float*)d_in[7];
    const float* ccb  = (const float*)d_in[8];
    const float* Wih  = (const float*)d_in[9];
    const float* Whh  = (const float*)d_in[10];
    const float* bih  = (const float*)d_in[11];
    const float* bhh  = (const float*)d_in[12];
    const float* lng  = (const float*)d_in[13];
    const float* lnb  = (const float*)d_in[14];
    const float* W1   = (const float*)d_in[15];
    const float* b1   = (const float*)d_in[16];
    const float* W2   = (const float*)d_in[17];
    const float* b2   = (const float*)d_in[18];
    const float* Wa   = (const float*)d_in[19];
    const float* ba   = (const float*)d_in[20];
    const float* Wb   = (const float*)d_in[21];
    const float* bb   = (const float*)d_in[22];

    float* cc_ws = (float*)d_ws;     // 640 floats
    float* out   = (float*)d_out;

    hipLaunchKernelGGL(phase1_kernel, dim3(1), dim3(640), 0, stream,
                       cc0, Wk, bk, Wq, bq, Wv, bv, ccg, ccb,
                       Wih, Whh, bih, bhh, lng, lnb, W1, b1, W2, b2, cc_ws);

    hipLaunchKernelGGL(phase2_kernel, dim3(NSLOT), dim3(64), 0, stream,
                       Wa, ba, Wb, bb, cc_ws, out);
}

// Round 5
// 261.261 us; speedup vs baseline: 2.3052x; 1.1076x over previous
//
#include <hip/hip_runtime.h>
#include <math.h>

#define NCLU 10
#define D    64
#define NSLOT 4096

typedef unsigned int   u32;
typedef unsigned short u16;

typedef __attribute__((ext_vector_type(8))) short  bf16x8;
typedef __attribute__((ext_vector_type(4))) float  f32x4;

__device__ __forceinline__ u16 f2bf_rne(float f) {
    u32 u = __float_as_uint(f);
    return (u16)((u + 0x7fffu + ((u >> 16) & 1u)) >> 16);
}

// ---- f32 broadcast dots: x from wave-uniform LDS row, weights in float4 regs ----
__device__ __forceinline__ float dotb64(const float* __restrict__ xrow, const float4* w4) {
    const float4* x4 = (const float4*)xrow;
    float a0 = 0.f, a1 = 0.f, a2 = 0.f, a3 = 0.f;
#pragma unroll
    for (int jj = 0; jj < 16; ++jj) {
        float4 xv = x4[jj], wv = w4[jj];
        a0 += wv.x * xv.x; a1 += wv.y * xv.y; a2 += wv.z * xv.z; a3 += wv.w * xv.w;
    }
    return (a0 + a1) + (a2 + a3);
}
__device__ __forceinline__ float dotb128(const float* __restrict__ xrow, const float4* w4) {
    const float4* x4 = (const float4*)xrow;
    float a0 = 0.f, a1 = 0.f, a2 = 0.f, a3 = 0.f;
#pragma unroll
    for (int jj = 0; jj < 32; ++jj) {
        float4 xv = x4[jj], wv = w4[jj];
        a0 += wv.x * xv.x; a1 += wv.y * xv.y; a2 += wv.z * xv.z; a3 += wv.w * xv.w;
    }
    return (a0 + a1) + (a2 + a3);
}

__device__ __forceinline__ float wred(float v) {
#pragma unroll
    for (int off = 32; off > 0; off >>= 1) v += __shfl_xor(v, off);
    return v;
}

// ---------------- Phase 1: weight-stationary slot-attention refinement ----------------
// 1 block x 640 threads = 10 waves. Wave w owns one weight block in a UNIFORMLY-DEFINED
// float4 w4[32] (only the source pointer is divergent; static indices everywhere) so the
// array lives in VGPRs (~160 total), not scratch — the round-4 kernel spilled (VGPR=84).
__global__ __launch_bounds__(640) void phase1_kernel(
    const float* __restrict__ cc0,
    const float* __restrict__ Wk, const float* __restrict__ bk,
    const float* __restrict__ Wq, const float* __restrict__ bq,
    const float* __restrict__ Wv, const float* __restrict__ bv,
    const float* __restrict__ cc_g, const float* __restrict__ cc_b,
    const float* __restrict__ W_ih, const float* __restrict__ W_hh,
    const float* __restrict__ b_ih, const float* __restrict__ b_hh,
    const float* __restrict__ ln_g, const float* __restrict__ ln_b,
    const float* __restrict__ W1, const float* __restrict__ b1,
    const float* __restrict__ W2, const float* __restrict__ b2,
    float* __restrict__ cc_out)
{
    const int t = threadIdx.x;
    const int w = t >> 6;
    const int i = t & 63;

    __shared__ float ccl[NCLU][64];
    __shared__ float xl[NCLU][64];
    __shared__ float kl[NCLU][64];
    __shared__ float vl[NCLU][64];
    __shared__ float ql[NCLU][68];
    __shared__ float al[NCLU][12];
    __shared__ float ul[NCLU][64];
    __shared__ float hl[NCLU][64];
    __shared__ float tl[NCLU][128];
    __shared__ float gl[6][NCLU][64];
    __shared__ float dl[NCLU][64];

    const float g_cc = cc_g[i], b_cc = cc_b[i];
    const float g_ln = ln_g[i], b_ln = ln_b[i];

    // role-specific source pointer (wave-uniform divergence only)
    const float* srcp;
    float bias0 = 0.f, biask = 0.f;
    if (w == 0)      { srcp = Wq + i * 64;                     bias0 = bq[i]; }
    else if (w <= 3) { srcp = W_ih + ((w - 1) * 64 + i) * 64;  bias0 = b_ih[(w - 1) * 64 + i]; }
    else if (w <= 6) { srcp = W_hh + ((w - 4) * 64 + i) * 64;  bias0 = b_hh[(w - 4) * 64 + i]; }
    else if (w == 7) { srcp = Wk + i * 64;                     biask = bk[i]; }
    else if (w == 8) { srcp = Wv + i * 64;                     biask = bv[i]; }
    else             { srcp = W2 + i * 128;                    bias0 = b2[i]; }

    float4 w4[32];
#pragma unroll
    for (int jj = 0; jj < 16; ++jj) w4[jj] = ((const float4*)srcp)[jj];
#pragma unroll
    for (int jj = 16; jj < 32; ++jj) w4[jj] = make_float4(0.f, 0.f, 0.f, 0.f);
    if (w == 9) {
#pragma unroll
        for (int jj = 16; jj < 32; ++jj) w4[jj] = ((const float4*)srcp)[jj];
    }

    float c = cc0[w * 64 + i];
    ccl[w][i] = c;
    __syncthreads();

    // k, v from original cluster_centers (w7/w8 hold Wk/Wv initially)
    if (w == 7) {
#pragma unroll
        for (int n = 0; n < NCLU; ++n) kl[n][i] = dotb64(&ccl[n][0], w4) + biask;
    } else if (w == 8) {
#pragma unroll
        for (int n = 0; n < NCLU; ++n) vl[n][i] = dotb64(&ccl[n][0], w4) + biask;
    }
    __syncthreads();

    // w7/w8 swap to W1 halves
    if (w == 7) {
        const float4* p = (const float4*)(W1 + i * 64);
#pragma unroll
        for (int jj = 0; jj < 16; ++jj) w4[jj] = p[jj];
        bias0 = b1[i];
    } else if (w == 8) {
        const float4* p = (const float4*)(W1 + (64 + i) * 64);
#pragma unroll
        for (int jj = 0; jj < 16; ++jj) w4[jj] = p[jj];
        bias0 = b1[64 + i];
    }

    for (int it = 0; it < 3; ++it) {
        // LN(cc)
        {
            float s1 = wred(c), s2 = wred(c * c);
            float mu = s1 * (1.f / 64.f);
            float va = s2 * (1.f / 64.f) - mu * mu;
            xl[w][i] = (c - mu) * rsqrtf(va + 1e-5f) * g_cc + b_cc;
        }
        __syncthreads();

        // q (w0) concurrent with gh gates (w4-6)
        if (w == 0) {
#pragma unroll
            for (int n = 0; n < NCLU; ++n) ql[n][i] = dotb64(&xl[n][0], w4) + bias0;
        } else if (w >= 4 && w <= 6) {
#pragma unroll
            for (int n = 0; n < NCLU; ++n) gl[w - 1][n][i] = dotb64(&ccl[n][0], w4) + bias0;
        }
        __syncthreads();

        // attn
        if (i < NCLU) {
            const float4* kf = (const float4*)&kl[w][0];
            const float4* qf = (const float4*)&ql[i][0];
            float a0 = 0.f, a1 = 0.f, a2 = 0.f, a3 = 0.f;
#pragma unroll
            for (int jj = 0; jj < 16; ++jj) {
                float4 kv = kf[jj], qv = qf[jj];
                a0 += kv.x * qv.x; a1 += kv.y * qv.y; a2 += kv.z * qv.z; a3 += kv.w * qv.w;
            }
            al[w][i] = ((a0 + a1) + (a2 + a3)) * 0.125f;
        }
        __syncthreads();

        // softmax axis 0 + EPS
        if (t < NCLU) {
            float mx = -1e30f;
#pragma unroll
            for (int nn = 0; nn < NCLU; ++nn) mx = fmaxf(mx, al[nn][t]);
            float e[NCLU]; float s = 0.f;
#pragma unroll
            for (int nn = 0; nn < NCLU; ++nn) { e[nn] = __expf(al[nn][t] - mx); s += e[nn]; }
            float inv = 1.f / s;
#pragma unroll
            for (int nn = 0; nn < NCLU; ++nn) al[nn][t] = e[nn] * inv + 1e-8f;
        }
        __syncthreads();
        // row renormalize
        if (t < NCLU) {
            float s = 0.f;
#pragma unroll
            for (int m = 0; m < NCLU; ++m) s += al[t][m];
            float inv = 1.f / s;
#pragma unroll
            for (int m = 0; m < NCLU; ++m) al[t][m] *= inv;
        }
        __syncthreads();

        // updates = attn @ v
        {
            float u = 0.f;
#pragma unroll
            for (int m = 0; m < NCLU; ++m) u += al[w][m] * vl[m][i];
            ul[w][i] = u;
        }
        __syncthreads();

        // gi gates (w1-3)
        if (w >= 1 && w <= 3) {
#pragma unroll
            for (int n = 0; n < NCLU; ++n) gl[w - 1][n][i] = dotb64(&ul[n][0], w4) + bias0;
        }
        __syncthreads();

        // GRU combine
        {
            float ir = gl[0][w][i], iz = gl[1][w][i], inn = gl[2][w][i];
            float hr = gl[3][w][i], hz = gl[4][w][i], hn = gl[5][w][i];
            float r = 1.f / (1.f + __expf(-(ir + hr)));
            float z = 1.f / (1.f + __expf(-(iz + hz)));
            float nn2 = tanhf(inn + r * hn);
            c = (1.f - z) * nn2 + z * c;
        }

        // MLP LN
        {
            float s1 = wred(c), s2 = wred(c * c);
            float mu = s1 * (1.f / 64.f);
            float va = s2 * (1.f / 64.f) - mu * mu;
            hl[w][i] = (c - mu) * rsqrtf(va + 1e-5f) * g_ln + b_ln;
        }
        __syncthreads();

        // hidden = relu(h @ W1^T + b1)
        if (w == 7) {
#pragma unroll
            for (int n = 0; n < NCLU; ++n) tl[n][i] = fmaxf(dotb64(&hl[n][0], w4) + bias0, 0.f);
        } else if (w == 8) {
#pragma unroll
            for (int n = 0; n < NCLU; ++n) tl[n][64 + i] = fmaxf(dotb64(&hl[n][0], w4) + bias0, 0.f);
        }
        __syncthreads();

        // delta = hidden @ W2^T + b2 (w9)
        if (w == 9) {
#pragma unroll
            for (int n = 0; n < NCLU; ++n) dl[n][i] = dotb128(&tl[n][0], w4) + bias0;
        }
        __syncthreads();

        c += dl[w][i];
        ccl[w][i] = c;
        __syncthreads();
    }

    cc_out[w * 64 + i] = c;
}

// ---------------- Phase 2: bf16-MFMA per-slot MLP + max over clusters ----------------
// 4096 blocks x 64 threads = 1 wave per slot; no __syncthreads (wave-private LDS).
// Per layer: 8x mfma_f32_16x16x32_bf16 instead of 160 broadcast ds_reads.
// Weights: coalesced f32 loads -> bf16 -> stride-72 padded LDS (2-way banks = free).
// Fragment layouts (verified m89/m120): A[m=lane&15][k=quad*8+j]; B[k=quad*8+j][n=lane&15];
// D: col=lane&15, row=quad*4+reg.
#define WSTRIDE 72
__global__ __launch_bounds__(64) void phase2_kernel(
    const float* __restrict__ Wa, const float* __restrict__ ba,
    const float* __restrict__ Wb, const float* __restrict__ bb,
    const float* __restrict__ cc, float* __restrict__ out)
{
    const int s = blockIdx.x;
    const int l = threadIdx.x;
    const int quad = l >> 4;
    const int lc   = l & 15;

    __shared__ u16 Wlds[64 * WSTRIDE];   // 9216 B, padded rows
    __shared__ u16 hT[16 * WSTRIDE];     // 2304 B, h transposed [n][k]

    const float* wa = Wa + (size_t)s * 4096;
    const float* wb = Wb + (size_t)s * 4096;

    // ---- load Wa coalesced (lane l: chunk c -> row 4c+quad, cols 4*lc..+3) ----
    float4 rg[16];
#pragma unroll
    for (int cch = 0; cch < 16; ++cch)
        rg[cch] = *(const float4*)(wa + cch * 256 + l * 4);

    // ---- cvt + stage Wa into padded LDS ----
#pragma unroll
    for (int cch = 0; cch < 16; ++cch) {
        int row = cch * 4 + quad;
        u32 p0 = (u32)f2bf_rne(rg[cch].x) | ((u32)f2bf_rne(rg[cch].y) << 16);
        u32 p1 = (u32)f2bf_rne(rg[cch].z) | ((u32)f2bf_rne(rg[cch].w) << 16);
        uint2 pk; pk.x = p0; pk.y = p1;
        *(uint2*)(&Wlds[row * WSTRIDE + lc * 4]) = pk;
    }

    // ---- issue Wb loads now (in flight during layer-1 MFMAs) ----
#pragma unroll
    for (int cch = 0; cch < 16; ++cch)
        rg[cch] = *(const float4*)(wb + cch * 256 + l * 4);

    // ---- layer 1: D1 = Wa (64x64) @ cc^T (64x16-pad) ----
    f32x4 acc[4];
#pragma unroll
    for (int mt = 0; mt < 4; ++mt) acc[mt] = (f32x4){0.f, 0.f, 0.f, 0.f};

#pragma unroll
    for (int kt = 0; kt < 2; ++kt) {
        // B-frag: lane holds cc[n=lc][k0..k0+7] (zeros for n>=10)
        bf16x8 bf;
        if (lc < NCLU) {
            const float* cp = cc + lc * 64 + kt * 32 + quad * 8;
            float4 c0 = *(const float4*)cp;
            float4 c1 = *(const float4*)(cp + 4);
            bf[0] = (short)f2bf_rne(c0.x); bf[1] = (short)f2bf_rne(c0.y);
            bf[2] = (short)f2bf_rne(c0.z); bf[3] = (short)f2bf_rne(c0.w);
            bf[4] = (short)f2bf_rne(c1.x); bf[5] = (short)f2bf_rne(c1.y);
            bf[6] = (short)f2bf_rne(c1.z); bf[7] = (short)f2bf_rne(c1.w);
        } else {
#pragma unroll
            for (int j = 0; j < 8; ++j) bf[j] = 0;
        }
#pragma unroll
        for (int mt = 0; mt < 4; ++mt) {
            bf16x8 af = *(const bf16x8*)(&Wlds[(16 * mt + lc) * WSTRIDE + kt * 32 + quad * 8]);
            acc[mt] = __builtin_amdgcn_mfma_f32_16x16x32_bf16(af, bf, acc[mt], 0, 0, 0);
        }
    }

    // ---- epilogue L1: h = relu(D1 + ba[row]); store hT[n][k] for layer-2 B-frags ----
#pragma unroll
    for (int mt = 0; mt < 4; ++mt) {
        float4 bav = *(const float4*)(ba + s * 64 + 16 * mt + quad * 4);
        u16 h0 = f2bf_rne(fmaxf(acc[mt][0] + bav.x, 0.f));
        u16 h1 = f2bf_rne(fmaxf(acc[mt][1] + bav.y, 0.f));
        u16 h2 = f2bf_rne(fmaxf(acc[mt][2] + bav.z, 0.f));
        u16 h3 = f2bf_rne(fmaxf(acc[mt][3] + bav.w, 0.f));
        uint2 pk; pk.x = (u32)h0 | ((u32)h1 << 16); pk.y = (u32)h2 | ((u32)h3 << 16);
        // rows k = 16*mt + quad*4 .. +3, col n = lc
        *(uint2*)(&hT[lc * WSTRIDE + 16 * mt + quad * 4]) = pk;
    }

    // ---- stage Wb (reuse Wlds; compiler orders LDS WAR via lgkmcnt) ----
#pragma unroll
    for (int cch = 0; cch < 16; ++cch) {
        int row = cch * 4 + quad;
        u32 p0 = (u32)f2bf_rne(rg[cch].x) | ((u32)f2bf_rne(rg[cch].y) << 16);
        u32 p1 = (u32)f2bf_rne(rg[cch].z) | ((u32)f2bf_rne(rg[cch].w) << 16);
        uint2 pk; pk.x = p0; pk.y = p1;
        *(uint2*)(&Wlds[row * WSTRIDE + lc * 4]) = pk;
    }

    // ---- layer 2: D2 = Wb @ h ----
    f32x4 acc2[4];
#pragma unroll
    for (int mt = 0; mt < 4; ++mt) acc2[mt] = (f32x4){0.f, 0.f, 0.f, 0.f};
#pragma unroll
    for (int kt = 0; kt < 2; ++kt) {
        bf16x8 bf = *(const bf16x8*)(&hT[lc * WSTRIDE + kt * 32 + quad * 8]);
#pragma unroll
        for (int mt = 0; mt < 4; ++mt) {
            bf16x8 af = *(const bf16x8*)(&Wlds[(16 * mt + lc) * WSTRIDE + kt * 32 + quad * 8]);
            acc2[mt] = __builtin_amdgcn_mfma_f32_16x16x32_bf16(af, bf, acc2[mt], 0, 0, 0);
        }
    }

    // ---- max over clusters: butterfly over column lanes (n = lc), mask n>=10 ----
    const float NEG = -3.0e38f;
#pragma unroll
    for (int mt = 0; mt < 4; ++mt) {
#pragma unroll
        for (int r = 0; r < 4; ++r) {
            float v = (lc < NCLU) ? acc2[mt][r] : NEG;
#pragma unroll
            for (int off = 1; off < 16; off <<= 1)
                v = fmaxf(v, __shfl_xor(v, off));
            acc2[mt][r] = v;   // all 16 lanes of the quad-group now hold the max
        }
    }

    // ---- write out: lane lc<4 writes row 16*mt + 4*quad + lc ----
    if (lc < 4) {
#pragma unroll
        for (int mt = 0; mt < 4; ++mt) {
            int row = 16 * mt + 4 * quad + lc;
            out[s * 64 + row] = acc2[mt][lc] + bb[s * 64 + row];
        }
    }
}

extern "C" void kernel_launch(void* const* d_in, const int* in_sizes, int n_in,
                              void* d_out, int out_size, void* d_ws, size_t ws_size,
                              hipStream_t stream) {
    const float* cc0  = (const float*)d_in[0];
    const float* Wk   = (const float*)d_in[1];
    const float* bk   = (const float*)d_in[2];
    const float* Wq   = (const float*)d_in[3];
    const float* bq   = (const float*)d_in[4];
    const float* Wv   = (const float*)d_in[5];
    const float* bv   = (const float*)d_in[6];
    const float* ccg  = (const float*)d_in[7];
    const float* ccb  = (const float*)d_in[8];
    const float* Wih  = (const float*)d_in[9];
    const float* Whh  = (const float*)d_in[10];
    const float* bih  = (const float*)d_in[11];
    const float* bhh  = (const float*)d_in[12];
    const float* lng  = (const float*)d_in[13];
    const float* lnb  = (const float*)d_in[14];
    const float* W1   = (const float*)d_in[15];
    const float* b1   = (const float*)d_in[16];
    const float* W2   = (const float*)d_in[17];
    const float* b2   = (const float*)d_in[18];
    const float* Wa   = (const float*)d_in[19];
    const float* ba   = (const float*)d_in[20];
    const float* Wb   = (const float*)d_in[21];
    const float* bb   = (const float*)d_in[22];

    float* cc_ws = (float*)d_ws;     // 640 floats
    float* out   = (float*)d_out;

    hipLaunchKernelGGL(phase1_kernel, dim3(1), dim3(640), 0, stream,
                       cc0, Wk, bk, Wq, bq, Wv, bv, ccg, ccb,
                       Wih, Whh, bih, bhh, lng, lnb, W1, b1, W2, b2, cc_ws);

    hipLaunchKernelGGL(phase2_kernel, dim3(NSLOT), dim3(64), 0, stream,
                       Wa, ba, Wb, bb, cc_ws, out);
}

// Round 6
// 219.545 us; speedup vs baseline: 2.7432x; 1.1900x over previous
//
#include <hip/hip_runtime.h>
#include <math.h>

#define NCLU 10
#define D    64
#define NSLOT 4096

typedef unsigned int   u32;
typedef unsigned short u16;

typedef __attribute__((ext_vector_type(8))) short  bf16x8;
typedef __attribute__((ext_vector_type(4))) float  f32x4;

__device__ __forceinline__ u16 f2bf_rne(float f) {
    u32 u = __float_as_uint(f);
    return (u16)((u + 0x7fffu + ((u >> 16) & 1u)) >> 16);
}

__device__ __forceinline__ bf16x8 pack8(float4 a, float4 b) {
    bf16x8 r;
    r[0] = (short)f2bf_rne(a.x); r[1] = (short)f2bf_rne(a.y);
    r[2] = (short)f2bf_rne(a.z); r[3] = (short)f2bf_rne(a.w);
    r[4] = (short)f2bf_rne(b.x); r[5] = (short)f2bf_rne(b.y);
    r[6] = (short)f2bf_rne(b.z); r[7] = (short)f2bf_rne(b.w);
    return r;
}

__device__ __forceinline__ float wred(float v) {
#pragma unroll
    for (int off = 32; off > 0; off >>= 1) v += __shfl_xor(v, off);
    return v;
}

// Load a 64x64 f32 weight matrix as MFMA A-fragments (bf16): a[mt][kt], lane (quad,lc)
// holds W[16*mt+lc][kt*32 + quad*8 .. +7]. 32 VGPRs total per wave.
__device__ __forceinline__ void load_afrags64(bf16x8 a[4][2], const float* __restrict__ W,
                                              int lc, int quad) {
#pragma unroll
    for (int mt = 0; mt < 4; ++mt)
#pragma unroll
        for (int kt = 0; kt < 2; ++kt) {
            const float* p = W + (16 * mt + lc) * 64 + kt * 32 + quad * 8;
            a[mt][kt] = pack8(*(const float4*)p, *(const float4*)(p + 4));
        }
}

// Same for a 64x128 matrix, covering k-tiles ktbase..ktbase+1 (half of K=128).
__device__ __forceinline__ void load_afrags128(bf16x8 a[4][2], const float* __restrict__ W,
                                               int ktbase, int lc, int quad) {
#pragma unroll
    for (int mt = 0; mt < 4; ++mt)
#pragma unroll
        for (int kt = 0; kt < 2; ++kt) {
            const float* p = W + (16 * mt + lc) * 128 + (ktbase + kt) * 32 + quad * 8;
            a[mt][kt] = pack8(*(const float4*)p, *(const float4*)(p + 4));
        }
}

// B-fragment from f32 LDS state X[n][k] (row stride in floats): lane holds
// X[n=lc][ktglob*32 + quad*8 .. +7], zeros for n>=NCLU.
__device__ __forceinline__ bf16x8 bfrag(const float* __restrict__ xbase, int xstride,
                                        int lc, int quad, int ktglob) {
    if (lc < NCLU) {
        const float* p = xbase + lc * xstride + ktglob * 32 + quad * 8;
        return pack8(*(const float4*)p, *(const float4*)(p + 4));
    }
    bf16x8 z;
#pragma unroll
    for (int j = 0; j < 8; ++j) z[j] = 0;
    return z;
}

// D = A(64xK) @ X^T (+bias, opt relu) written to out[n=lc][ooff + dim].
// D layout: col=lane&15 (n), row=quad*4+reg (dim within 16-tile).
__device__ __forceinline__ void mm_apply(const bf16x8 a[4][2], const float* __restrict__ xbase,
                                         int xstride, int ktbase,
                                         float* __restrict__ obase, int ostride, int ooff,
                                         const float* __restrict__ bias, bool do_relu,
                                         int lc, int quad) {
    f32x4 acc[4];
#pragma unroll
    for (int mt = 0; mt < 4; ++mt) acc[mt] = (f32x4){0.f, 0.f, 0.f, 0.f};
#pragma unroll
    for (int kt = 0; kt < 2; ++kt) {
        bf16x8 b = bfrag(xbase, xstride, lc, quad, ktbase + kt);
#pragma unroll
        for (int mt = 0; mt < 4; ++mt)
            acc[mt] = __builtin_amdgcn_mfma_f32_16x16x32_bf16(a[mt][kt], b, acc[mt], 0, 0, 0);
    }
    if (lc < NCLU) {
#pragma unroll
        for (int mt = 0; mt < 4; ++mt) {
            float4 o;
            o.x = acc[mt][0]; o.y = acc[mt][1]; o.z = acc[mt][2]; o.w = acc[mt][3];
            if (bias) {
                float4 bv = *(const float4*)(bias + 16 * mt + 4 * quad);
                o.x += bv.x; o.y += bv.y; o.z += bv.z; o.w += bv.w;
            }
            if (do_relu) {
                o.x = fmaxf(o.x, 0.f); o.y = fmaxf(o.y, 0.f);
                o.z = fmaxf(o.z, 0.f); o.w = fmaxf(o.w, 0.f);
            }
            *(float4*)(obase + lc * ostride + ooff + 16 * mt + 4 * quad) = o;
        }
    }
}

// ---------------- Phase 1: MFMA weight-stationary slot-attention ----------------
// 1 block x 640 threads = 10 waves. Wave roles (weights live as 32-VGPR A-frag sets):
//  w0: Wq | w1-3: W_ih blocks | w4-6: W_hh blocks
//  w7: Wk (setup) then W1[0:64] | w8: Wv (setup) then W1[64:128] + W2[k 64:128]
//  w9: W2[k 0:64]
// __launch_bounds__(640,3): 3 waves/EU is this block's true occupancy -> 170-VGPR cap
// (rounds 4/5 spilled at the default ~85 cap).
__global__ __launch_bounds__(640, 3) void phase1_kernel(
    const float* __restrict__ cc0,
    const float* __restrict__ Wk, const float* __restrict__ bk,
    const float* __restrict__ Wq, const float* __restrict__ bq,
    const float* __restrict__ Wv, const float* __restrict__ bv,
    const float* __restrict__ cc_g, const float* __restrict__ cc_b,
    const float* __restrict__ W_ih, const float* __restrict__ W_hh,
    const float* __restrict__ b_ih, const float* __restrict__ b_hh,
    const float* __restrict__ ln_g, const float* __restrict__ ln_b,
    const float* __restrict__ W1, const float* __restrict__ b1,
    const float* __restrict__ W2, const float* __restrict__ b2,
    float* __restrict__ cc_out)
{
    const int t = threadIdx.x;
    const int w = t >> 6;
    const int i = t & 63;
    const int quad = i >> 4;
    const int lc   = i & 15;

    __shared__ float ccl[NCLU][68];
    __shared__ float xl[NCLU][68];
    __shared__ float kl[NCLU][68];
    __shared__ float vl[NCLU][68];
    __shared__ float ql[NCLU][68];
    __shared__ float ul[NCLU][68];
    __shared__ float hl[NCLU][68];
    __shared__ float dl9[NCLU][68];
    __shared__ float dl8[NCLU][68];
    __shared__ float tl[NCLU][132];
    __shared__ float gl[6][NCLU][68];
    __shared__ float al[NCLU][12];

    const float g_cc = cc_g[i], b_cc = cc_b[i];
    const float g_ln = ln_g[i], b_ln = ln_b[i];

    // ---- weight fragments (per-wave role; arrays are 32 VGPRs each) ----
    bf16x8 afrA[4][2], afrB[4][2];
#pragma unroll
    for (int mt = 0; mt < 4; ++mt)
#pragma unroll
        for (int kt = 0; kt < 2; ++kt) {
#pragma unroll
            for (int j = 0; j < 8; ++j) { afrA[mt][kt][j] = 0; afrB[mt][kt][j] = 0; }
        }

    const float* biasA = nullptr;   // bias pointer for afrA's matmul
    if (w == 0)      { load_afrags64(afrA, Wq, lc, quad);                    biasA = bq; }
    else if (w <= 3) { load_afrags64(afrA, W_ih + (w - 1) * 64 * 64, lc, quad); biasA = b_ih + (w - 1) * 64; }
    else if (w <= 6) { load_afrags64(afrA, W_hh + (w - 4) * 64 * 64, lc, quad); biasA = b_hh + (w - 4) * 64; }
    else if (w == 7) { load_afrags64(afrA, Wk, lc, quad); }   // swapped to W1-lo after kv
    else if (w == 8) { load_afrags64(afrA, Wv, lc, quad);     // swapped to W1-hi after kv
                       load_afrags128(afrB, W2, 2, lc, quad); }
    else             { load_afrags128(afrA, W2, 0, lc, quad); biasA = b2; }

    float c = cc0[w * 64 + i];
    ccl[w][i] = c;
    __syncthreads();

    // ---- k, v from original cluster_centers ----
    if (w == 7)      mm_apply(afrA, &ccl[0][0], 68, 0, &kl[0][0], 68, 0, bk, false, lc, quad);
    else if (w == 8) mm_apply(afrA, &ccl[0][0], 68, 0, &vl[0][0], 68, 0, bv, false, lc, quad);
    __syncthreads();

    // swap w7/w8 to W1 halves (one-time global frag loads, overlap with iter-1 front)
    if (w == 7)      { load_afrags64(afrA, W1, lc, quad);            biasA = b1; }
    else if (w == 8) { load_afrags64(afrA, W1 + 64 * 64, lc, quad);  biasA = b1 + 64; }

    for (int it = 0; it < 3; ++it) {
        // ---- LN(cc) ----
        {
            float s1 = wred(c), s2 = wred(c * c);
            float mu = s1 * (1.f / 64.f);
            float va = s2 * (1.f / 64.f) - mu * mu;
            xl[w][i] = (c - mu) * rsqrtf(va + 1e-5f) * g_cc + b_cc;
        }
        __syncthreads();

        // ---- q (w0, xl) concurrent with gh gates (w4-6, prev ccl) ----
        if (w == 0)
            mm_apply(afrA, &xl[0][0], 68, 0, &ql[0][0], 68, 0, biasA, false, lc, quad);
        else if (w >= 4 && w <= 6)
            mm_apply(afrA, &ccl[0][0], 68, 0, &gl[w - 1][0][0], 68, 0, biasA, false, lc, quad);
        __syncthreads();

        // ---- attn[n][m] = temp * <k[n], q[m]>, wave n, lanes m<10 ----
        if (i < NCLU) {
            const float4* kf = (const float4*)&kl[w][0];
            const float4* qf = (const float4*)&ql[i][0];
            float a0 = 0.f, a1 = 0.f, a2 = 0.f, a3 = 0.f;
#pragma unroll
            for (int jj = 0; jj < 16; ++jj) {
                float4 kv = kf[jj], qv = qf[jj];
                a0 += kv.x * qv.x; a1 += kv.y * qv.y; a2 += kv.z * qv.z; a3 += kv.w * qv.w;
            }
            al[w][i] = ((a0 + a1) + (a2 + a3)) * 0.125f;
        }
        __syncthreads();

        // ---- softmax over axis 0 + EPS ----
        if (t < NCLU) {
            float mx = -1e30f;
#pragma unroll
            for (int nn = 0; nn < NCLU; ++nn) mx = fmaxf(mx, al[nn][t]);
            float e[NCLU]; float s = 0.f;
#pragma unroll
            for (int nn = 0; nn < NCLU; ++nn) { e[nn] = __expf(al[nn][t] - mx); s += e[nn]; }
            float inv = 1.f / s;
#pragma unroll
            for (int nn = 0; nn < NCLU; ++nn) al[nn][t] = e[nn] * inv + 1e-8f;
        }
        __syncthreads();
        // ---- row renormalize ----
        if (t < NCLU) {
            float s = 0.f;
#pragma unroll
            for (int m = 0; m < NCLU; ++m) s += al[t][m];
            float inv = 1.f / s;
#pragma unroll
            for (int m = 0; m < NCLU; ++m) al[t][m] *= inv;
        }
        __syncthreads();

        // ---- updates = attn @ v ----
        {
            float u = 0.f;
#pragma unroll
            for (int m = 0; m < NCLU; ++m) u += al[w][m] * vl[m][i];
            ul[w][i] = u;
        }
        __syncthreads();

        // ---- gi gates (w1-3, from ul) ----
        if (w >= 1 && w <= 3)
            mm_apply(afrA, &ul[0][0], 68, 0, &gl[w - 1][0][0], 68, 0, biasA, false, lc, quad);
        __syncthreads();

        // ---- GRU combine + MLP LN (wave == row) ----
        {
            float ir = gl[0][w][i], iz = gl[1][w][i], inn = gl[2][w][i];
            float hr = gl[3][w][i], hz = gl[4][w][i], hn = gl[5][w][i];
            float r = 1.f / (1.f + __expf(-(ir + hr)));
            float z = 1.f / (1.f + __expf(-(iz + hz)));
            float nn2 = tanhf(inn + r * hn);
            c = (1.f - z) * nn2 + z * c;

            float s1 = wred(c), s2 = wred(c * c);
            float mu = s1 * (1.f / 64.f);
            float va = s2 * (1.f / 64.f) - mu * mu;
            hl[w][i] = (c - mu) * rsqrtf(va + 1e-5f) * g_ln + b_ln;
        }
        __syncthreads();

        // ---- hidden = relu(h @ W1^T + b1): w7 -> tl[:,0:64], w8 -> tl[:,64:128] ----
        if (w == 7)
            mm_apply(afrA, &hl[0][0], 68, 0, &tl[0][0], 132, 0, biasA, true, lc, quad);
        else if (w == 8)
            mm_apply(afrA, &hl[0][0], 68, 0, &tl[0][0], 132, 64, biasA, true, lc, quad);
        __syncthreads();

        // ---- delta = hidden @ W2^T + b2: w9 k[0:64] (+b2), w8 k[64:128] ----
        if (w == 9)
            mm_apply(afrA, &tl[0][0], 132, 0, &dl9[0][0], 68, 0, biasA, false, lc, quad);
        else if (w == 8)
            mm_apply(afrB, &tl[0][0], 132, 2, &dl8[0][0], 68, 0, nullptr, false, lc, quad);
        __syncthreads();

        // ---- residual add, commit ----
        c += dl9[w][i] + dl8[w][i];
        ccl[w][i] = c;
        __syncthreads();
    }

    cc_out[w * 64 + i] = c;
}

// ---------------- Phase 2: bf16-MFMA per-slot MLP + max over clusters ----------------
// (unchanged from round 5 — correctness-proven; isolating the phase-1 change)
#define WSTRIDE 72
__global__ __launch_bounds__(64) void phase2_kernel(
    const float* __restrict__ Wa, const float* __restrict__ ba,
    const float* __restrict__ Wb, const float* __restrict__ bb,
    const float* __restrict__ cc, float* __restrict__ out)
{
    const int s = blockIdx.x;
    const int l = threadIdx.x;
    const int quad = l >> 4;
    const int lc   = l & 15;

    __shared__ u16 Wlds[64 * WSTRIDE];
    __shared__ u16 hT[16 * WSTRIDE];

    const float* wa = Wa + (size_t)s * 4096;
    const float* wb = Wb + (size_t)s * 4096;

    float4 rg[16];
#pragma unroll
    for (int cch = 0; cch < 16; ++cch)
        rg[cch] = *(const float4*)(wa + cch * 256 + l * 4);

#pragma unroll
    for (int cch = 0; cch < 16; ++cch) {
        int row = cch * 4 + quad;
        u32 p0 = (u32)f2bf_rne(rg[cch].x) | ((u32)f2bf_rne(rg[cch].y) << 16);
        u32 p1 = (u32)f2bf_rne(rg[cch].z) | ((u32)f2bf_rne(rg[cch].w) << 16);
        uint2 pk; pk.x = p0; pk.y = p1;
        *(uint2*)(&Wlds[row * WSTRIDE + lc * 4]) = pk;
    }

#pragma unroll
    for (int cch = 0; cch < 16; ++cch)
        rg[cch] = *(const float4*)(wb + cch * 256 + l * 4);

    f32x4 acc[4];
#pragma unroll
    for (int mt = 0; mt < 4; ++mt) acc[mt] = (f32x4){0.f, 0.f, 0.f, 0.f};

#pragma unroll
    for (int kt = 0; kt < 2; ++kt) {
        bf16x8 bf;
        if (lc < NCLU) {
            const float* cp = cc + lc * 64 + kt * 32 + quad * 8;
            bf = pack8(*(const float4*)cp, *(const float4*)(cp + 4));
        } else {
#pragma unroll
            for (int j = 0; j < 8; ++j) bf[j] = 0;
        }
#pragma unroll
        for (int mt = 0; mt < 4; ++mt) {
            bf16x8 af = *(const bf16x8*)(&Wlds[(16 * mt + lc) * WSTRIDE + kt * 32 + quad * 8]);
            acc[mt] = __builtin_amdgcn_mfma_f32_16x16x32_bf16(af, bf, acc[mt], 0, 0, 0);
        }
    }

#pragma unroll
    for (int mt = 0; mt < 4; ++mt) {
        float4 bav = *(const float4*)(ba + s * 64 + 16 * mt + quad * 4);
        u16 h0 = f2bf_rne(fmaxf(acc[mt][0] + bav.x, 0.f));
        u16 h1 = f2bf_rne(fmaxf(acc[mt][1] + bav.y, 0.f));
        u16 h2 = f2bf_rne(fmaxf(acc[mt][2] + bav.z, 0.f));
        u16 h3 = f2bf_rne(fmaxf(acc[mt][3] + bav.w, 0.f));
        uint2 pk; pk.x = (u32)h0 | ((u32)h1 << 16); pk.y = (u32)h2 | ((u32)h3 << 16);
        *(uint2*)(&hT[lc * WSTRIDE + 16 * mt + quad * 4]) = pk;
    }

#pragma unroll
    for (int cch = 0; cch < 16; ++cch) {
        int row = cch * 4 + quad;
        u32 p0 = (u32)f2bf_rne(rg[cch].x) | ((u32)f2bf_rne(rg[cch].y) << 16);
        u32 p1 = (u32)f2bf_rne(rg[cch].z) | ((u32)f2bf_rne(rg[cch].w) << 16);
        uint2 pk; pk.x = p0; pk.y = p1;
        *(uint2*)(&Wlds[row * WSTRIDE + lc * 4]) = pk;
    }

    f32x4 acc2[4];
#pragma unroll
    for (int mt = 0; mt < 4; ++mt) acc2[mt] = (f32x4){0.f, 0.f, 0.f, 0.f};
#pragma unroll
    for (int kt = 0; kt < 2; ++kt) {
        bf16x8 bf = *(const bf16x8*)(&hT[lc * WSTRIDE + kt * 32 + quad * 8]);
#pragma unroll
        for (int mt = 0; mt < 4; ++mt) {
            bf16x8 af = *(const bf16x8*)(&Wlds[(16 * mt + lc) * WSTRIDE + kt * 32 + quad * 8]);
            acc2[mt] = __builtin_amdgcn_mfma_f32_16x16x32_bf16(af, bf, acc2[mt], 0, 0, 0);
        }
    }

    const float NEG = -3.0e38f;
#pragma unroll
    for (int mt = 0; mt < 4; ++mt) {
#pragma unroll
        for (int r = 0; r < 4; ++r) {
            float v = (lc < NCLU) ? acc2[mt][r] : NEG;
#pragma unroll
            for (int off = 1; off < 16; off <<= 1)
                v = fmaxf(v, __shfl_xor(v, off));
            acc2[mt][r] = v;
        }
    }

    if (lc < 4) {
#pragma unroll
        for (int mt = 0; mt < 4; ++mt) {
            int row = 16 * mt + 4 * quad + lc;
            out[s * 64 + row] = acc2[mt][lc] + bb[s * 64 + row];
        }
    }
}

extern "C" void kernel_launch(void* const* d_in, const int* in_sizes, int n_in,
                              void* d_out, int out_size, void* d_ws, size_t ws_size,
                              hipStream_t stream) {
    const float* cc0  = (const float*)d_in[0];
    const float* Wk   = (const float*)d_in[1];
    const float* bk   = (const float*)d_in[2];
    const float* Wq   = (const float*)d_in[3];
    const float* bq   = (const float*)d_in[4];
    const float* Wv   = (const float*)d_in[5];
    const float* bv   = (const float*)d_in[6];
    const float* ccg  = (const float*)d_in[7];
    const float* ccb  = (const float*)d_in[8];
    const float* Wih  = (const float*)d_in[9];
    const float* Whh  = (const float*)d_in[10];
    const float* bih  = (const float*)d_in[11];
    const float* bhh  = (const float*)d_in[12];
    const float* lng  = (const float*)d_in[13];
    const float* lnb  = (const float*)d_in[14];
    const float* W1   = (const float*)d_in[15];
    const float* b1   = (const float*)d_in[16];
    const float* W2   = (const float*)d_in[17];
    const float* b2   = (const float*)d_in[18];
    const float* Wa   = (const float*)d_in[19];
    const float* ba   = (const float*)d_in[20];
    const float* Wb   = (const float*)d_in[21];
    const float* bb   = (const float*)d_in[22];

    float* cc_ws = (float*)d_ws;     // 640 floats
    float* out   = (float*)d_out;

    hipLaunchKernelGGL(phase1_kernel, dim3(1), dim3(640), 0, stream,
                       cc0, Wk, bk, Wq, bq, Wv, bv, ccg, ccb,
                       Wih, Whh, bih, bhh, lng, lnb, W1, b1, W2, b2, cc_ws);

    hipLaunchKernelGGL(phase2_kernel, dim3(NSLOT), dim3(64), 0, stream,
                       Wa, ba, Wb, bb, cc_ws, out);
}